// Round 1
// baseline (416.334 us; speedup 1.0000x reference)
//
#include <hip/hip_runtime.h>

// GCN 3-layer + MLP head, fp32 throughout.
// Pipeline per launch (deterministic up to atomic CSR-fill order, which only
// perturbs fp32 summation order by ~1e-6):
//   1) in-degree count -> dis = rsqrt(deg+1)
//   2) exclusive scan -> row_ptr; atomic fill -> csr_src (CSR by dst)
//   3) per layer: g = dis .* (h @ W)  [tiled vector-FMA GEMM]
//                 h = relu(dis_i * (sum_{e->i} g[src_e] + g_i) + b)  [wave/node gather]
//   4) t = h @ Wo1 + bo1 ; out = t @ Wo2 + bo2

#define DHID 128

// ---------------- CSR build ----------------

__global__ __launch_bounds__(256) void k_count(const int* __restrict__ ei, int E,
                                               int* __restrict__ cnt) {
  int e = blockIdx.x * 256 + threadIdx.x;
  if (e < E) atomicAdd(&cnt[ei[E + e]], 1);
}

__global__ __launch_bounds__(256) void k_dis(const int* __restrict__ cnt,
                                             float* __restrict__ dis, int M) {
  int i = blockIdx.x * 256 + threadIdx.x;
  if (i < M) dis[i] = rsqrtf((float)cnt[i] + 1.0f);
}

__global__ __launch_bounds__(256) void k_scan1(const int* __restrict__ cnt,
                                               int* __restrict__ rp,
                                               int* __restrict__ blk, int M) {
  __shared__ int s[256];
  int tid = threadIdx.x;
  int i = blockIdx.x * 256 + tid;
  int v = (i < M) ? cnt[i] : 0;
  s[tid] = v;
  __syncthreads();
  for (int off = 1; off < 256; off <<= 1) {
    int t = (tid >= off) ? s[tid - off] : 0;
    __syncthreads();
    s[tid] += t;
    __syncthreads();
  }
  if (i < M) rp[i] = s[tid] - v;  // exclusive within block
  if (tid == 255) blk[blockIdx.x] = s[255];
}

__global__ void k_scan2(int* blk, int n) {  // n <= 256
  __shared__ int s[256];
  int tid = threadIdx.x;
  int v = (tid < n) ? blk[tid] : 0;
  s[tid] = v;
  __syncthreads();
  for (int off = 1; off < 256; off <<= 1) {
    int t = (tid >= off) ? s[tid - off] : 0;
    __syncthreads();
    s[tid] += t;
    __syncthreads();
  }
  if (tid < n) blk[tid] = s[tid] - v;  // exclusive
}

__global__ __launch_bounds__(256) void k_scan3(int* __restrict__ rp,
                                               const int* __restrict__ blk,
                                               int* __restrict__ fill, int M, int E) {
  int i = blockIdx.x * 256 + threadIdx.x;
  if (i < M) {
    int v = rp[i] + blk[blockIdx.x];
    rp[i] = v;
    fill[i] = v;
  }
  if (i == 0) rp[M] = E;
}

__global__ __launch_bounds__(256) void k_fill(const int* __restrict__ ei, int E,
                                              int* __restrict__ fill,
                                              int* __restrict__ csr) {
  int e = blockIdx.x * 256 + threadIdx.x;
  if (e < E) {
    int d = ei[E + e];
    int pos = atomicAdd(&fill[d], 1);
    csr[pos] = ei[e];
  }
}

// ---------------- GEMM: [M,128] @ [128,128], fp32 vector FMA ----------------
// MODE 0: out = dis[row] * (H@W)      (pre-aggregation g buffer)
// MODE 1: out = H@W + bias            (MLP hidden)
// Tile: 64 rows/block, 256 threads; thread = 8 rows x 4 cols; H tile in LDS.
// LDS reads are wave-broadcast (all 32 lanes of a half-wave read same addr).

template <int MODE>
__global__ __launch_bounds__(256) void k_gemm128(const float* __restrict__ H,
                                                 const float* __restrict__ W,
                                                 const float* __restrict__ dis,
                                                 const float* __restrict__ bias,
                                                 float* __restrict__ out, int M) {
  __shared__ float4 Hs[64 * 32];  // 32 KB
  int tid = threadIdx.x;
  int row0 = blockIdx.x * 64;
  const float4* H4 = (const float4*)H;
#pragma unroll
  for (int i = 0; i < 8; i++) {
    int slot = tid + i * 256;  // 0..2047
    int r = slot >> 5, c4 = slot & 31;
    int gr = row0 + r;
    Hs[slot] = (gr < M) ? H4[(size_t)gr * 32 + c4] : make_float4(0.f, 0.f, 0.f, 0.f);
  }
  __syncthreads();

  int c4 = tid & 31;          // output col group (4 cols)
  int r0 = (tid >> 5) * 8;    // 8 rows per thread
  const float4* W4 = (const float4*)W;  // W[k][c] row-major -> W4[k*32+c4]
  float4 acc[8];
#pragma unroll
  for (int r = 0; r < 8; r++) acc[r] = make_float4(0.f, 0.f, 0.f, 0.f);

  for (int k4 = 0; k4 < 32; k4++) {
    float4 w0 = W4[(k4 * 4 + 0) * 32 + c4];
    float4 w1 = W4[(k4 * 4 + 1) * 32 + c4];
    float4 w2 = W4[(k4 * 4 + 2) * 32 + c4];
    float4 w3 = W4[(k4 * 4 + 3) * 32 + c4];
#pragma unroll
    for (int r = 0; r < 8; r++) {
      float4 h = Hs[(r0 + r) * 32 + k4];
      acc[r].x = fmaf(h.w, w3.x, fmaf(h.z, w2.x, fmaf(h.y, w1.x, fmaf(h.x, w0.x, acc[r].x))));
      acc[r].y = fmaf(h.w, w3.y, fmaf(h.z, w2.y, fmaf(h.y, w1.y, fmaf(h.x, w0.y, acc[r].y))));
      acc[r].z = fmaf(h.w, w3.z, fmaf(h.z, w2.z, fmaf(h.y, w1.z, fmaf(h.x, w0.z, acc[r].z))));
      acc[r].w = fmaf(h.w, w3.w, fmaf(h.z, w2.w, fmaf(h.y, w1.w, fmaf(h.x, w0.w, acc[r].w))));
    }
  }

#pragma unroll
  for (int r = 0; r < 8; r++) {
    int gr = row0 + r0 + r;
    if (gr < M) {
      float4 v = acc[r];
      if (MODE == 0) {
        float d = dis[gr];
        v.x *= d; v.y *= d; v.z *= d; v.w *= d;
      } else {
        float4 b = ((const float4*)bias)[c4];
        v.x += b.x; v.y += b.y; v.z += b.z; v.w += b.w;
      }
      ((float4*)out)[(size_t)gr * 32 + c4] = v;
    }
  }
}

// ---------------- GEMM: [M,128] @ [128,64] + bias -> out ----------------
__global__ __launch_bounds__(256) void k_gemm64(const float* __restrict__ H,
                                                const float* __restrict__ W,
                                                const float* __restrict__ bias,
                                                float* __restrict__ out, int M) {
  __shared__ float4 Hs[64 * 32];  // 32 KB
  int tid = threadIdx.x;
  int row0 = blockIdx.x * 64;
  const float4* H4 = (const float4*)H;
#pragma unroll
  for (int i = 0; i < 8; i++) {
    int slot = tid + i * 256;
    int r = slot >> 5, c4 = slot & 31;
    int gr = row0 + r;
    Hs[slot] = (gr < M) ? H4[(size_t)gr * 32 + c4] : make_float4(0.f, 0.f, 0.f, 0.f);
  }
  __syncthreads();

  int c4 = tid & 15;         // 16 col groups x 4 = 64 cols
  int r0 = (tid >> 4) * 4;   // 16 row groups x 4 = 64 rows
  const float4* W4 = (const float4*)W;  // W[k][c], N=64 -> W4[k*16+c4]
  float4 acc[4];
#pragma unroll
  for (int r = 0; r < 4; r++) acc[r] = make_float4(0.f, 0.f, 0.f, 0.f);

  for (int k4 = 0; k4 < 32; k4++) {
    float4 w0 = W4[(k4 * 4 + 0) * 16 + c4];
    float4 w1 = W4[(k4 * 4 + 1) * 16 + c4];
    float4 w2 = W4[(k4 * 4 + 2) * 16 + c4];
    float4 w3 = W4[(k4 * 4 + 3) * 16 + c4];
#pragma unroll
    for (int r = 0; r < 4; r++) {
      float4 h = Hs[(r0 + r) * 32 + k4];
      acc[r].x = fmaf(h.w, w3.x, fmaf(h.z, w2.x, fmaf(h.y, w1.x, fmaf(h.x, w0.x, acc[r].x))));
      acc[r].y = fmaf(h.w, w3.y, fmaf(h.z, w2.y, fmaf(h.y, w1.y, fmaf(h.x, w0.y, acc[r].y))));
      acc[r].z = fmaf(h.w, w3.z, fmaf(h.z, w2.z, fmaf(h.y, w1.z, fmaf(h.x, w0.z, acc[r].z))));
      acc[r].w = fmaf(h.w, w3.w, fmaf(h.z, w2.w, fmaf(h.y, w1.w, fmaf(h.x, w0.w, acc[r].w))));
    }
  }

  float4 b = ((const float4*)bias)[c4];
#pragma unroll
  for (int r = 0; r < 4; r++) {
    int gr = row0 + r0 + r;
    if (gr < M) {
      float4 v = acc[r];
      v.x += b.x; v.y += b.y; v.z += b.z; v.w += b.w;
      ((float4*)out)[(size_t)gr * 16 + c4] = v;
    }
  }
}

// ---------------- Aggregation: one wave per node ----------------
// h_out[i] = relu( dis[i] * (sum_{e: dst=i} g[src_e] + g[i]) + b )
__global__ __launch_bounds__(256) void k_agg(const float* __restrict__ g,
                                             const int* __restrict__ csr,
                                             const int* __restrict__ rp,
                                             const float* __restrict__ dis,
                                             const float* __restrict__ bias,
                                             float* __restrict__ out, int M, int relu) {
  int wid = (int)((blockIdx.x * 256 + threadIdx.x) >> 6);  // node id
  int lane = threadIdx.x & 63;
  if (wid >= M) return;
  const float2* g2 = (const float2*)g;
  float2 acc = g2[(size_t)wid * 64 + lane];  // self-loop term g_i
  int start = rp[wid], end = rp[wid + 1];
  for (int base = start; base < end; base += 64) {
    int n = end - base;
    if (n > 64) n = 64;
    int idx = (lane < n) ? csr[base + lane] : 0;
    int j = 0;
    for (; j + 4 <= n; j += 4) {
      int s0 = __shfl(idx, j, 64);
      int s1 = __shfl(idx, j + 1, 64);
      int s2 = __shfl(idx, j + 2, 64);
      int s3 = __shfl(idx, j + 3, 64);
      float2 v0 = g2[(size_t)s0 * 64 + lane];
      float2 v1 = g2[(size_t)s1 * 64 + lane];
      float2 v2 = g2[(size_t)s2 * 64 + lane];
      float2 v3 = g2[(size_t)s3 * 64 + lane];
      acc.x += (v0.x + v1.x) + (v2.x + v3.x);
      acc.y += (v0.y + v1.y) + (v2.y + v3.y);
    }
    for (; j < n; ++j) {
      int s0 = __shfl(idx, j, 64);
      float2 v = g2[(size_t)s0 * 64 + lane];
      acc.x += v.x;
      acc.y += v.y;
    }
  }
  float di = dis[wid];
  float2 b = ((const float2*)bias)[lane];
  float rx = fmaf(di, acc.x, b.x);
  float ry = fmaf(di, acc.y, b.y);
  if (relu) {
    rx = fmaxf(rx, 0.f);
    ry = fmaxf(ry, 0.f);
  }
  ((float2*)out)[(size_t)wid * 64 + lane] = make_float2(rx, ry);
}

// ---------------- launch ----------------

extern "C" void kernel_launch(void* const* d_in, const int* in_sizes, int n_in,
                              void* d_out, int out_size, void* d_ws, size_t ws_size,
                              hipStream_t stream) {
  const float* x = (const float*)d_in[0];
  const int* ei = (const int*)d_in[1];
  const float* W1 = (const float*)d_in[2];
  const float* b1 = (const float*)d_in[3];
  const float* W2 = (const float*)d_in[4];
  const float* b2 = (const float*)d_in[5];
  const float* W3 = (const float*)d_in[6];
  const float* b3 = (const float*)d_in[7];
  const float* Wo1 = (const float*)d_in[8];
  const float* bo1 = (const float*)d_in[9];
  const float* Wo2 = (const float*)d_in[10];
  const float* bo2 = (const float*)d_in[11];
  float* out = (float*)d_out;

  int M = in_sizes[0] / DHID;  // 50000
  int E = in_sizes[1] / 2;     // 800000

  // workspace layout (~61 MB total)
  char* ws = (char*)d_ws;
  float* dis = (float*)(ws + 0);                 // M floats
  int* cnt = (int*)(ws + (1 << 20));             // M ints
  int* rp = (int*)(ws + (2 << 20));              // M+1 ints
  int* fill = (int*)(ws + (3 << 20));            // M ints
  int* blk = (int*)(ws + (4 << 20));             // <=256 ints
  int* csr = (int*)(ws + (5 << 20));             // E ints (3.2 MB)
  float* g = (float*)(ws + (9ull << 20));        // M*128 floats (25.6 MB)
  float* h = (float*)(ws + (35ull << 20));       // M*128 floats (25.6 MB)

  int gE = (E + 255) / 256;
  int gM = (M + 255) / 256;   // 196 (<=256 required by k_scan2)
  int gG = (M + 63) / 64;     // GEMM row tiles
  int gA = (M + 3) / 4;       // 4 waves/block, wave per node

  // CSR build
  hipMemsetAsync(cnt, 0, (size_t)M * sizeof(int), stream);
  k_count<<<gE, 256, 0, stream>>>(ei, E, cnt);
  k_dis<<<gM, 256, 0, stream>>>(cnt, dis, M);
  k_scan1<<<gM, 256, 0, stream>>>(cnt, rp, blk, M);
  k_scan2<<<1, 256, 0, stream>>>(blk, gM);
  k_scan3<<<gM, 256, 0, stream>>>(rp, blk, fill, M, E);
  k_fill<<<gE, 256, 0, stream>>>(ei, E, fill, csr);

  // GCN layer 1 (reads x)
  k_gemm128<0><<<gG, 256, 0, stream>>>(x, W1, dis, nullptr, g, M);
  k_agg<<<gA, 256, 0, stream>>>(g, csr, rp, dis, b1, h, M, 1);
  // GCN layer 2
  k_gemm128<0><<<gG, 256, 0, stream>>>(h, W2, dis, nullptr, g, M);
  k_agg<<<gA, 256, 0, stream>>>(g, csr, rp, dis, b2, h, M, 1);
  // GCN layer 3
  k_gemm128<0><<<gG, 256, 0, stream>>>(h, W3, dis, nullptr, g, M);
  k_agg<<<gA, 256, 0, stream>>>(g, csr, rp, dis, b3, h, M, 1);
  // MLP head
  k_gemm128<1><<<gG, 256, 0, stream>>>(h, Wo1, nullptr, bo1, g, M);
  k_gemm64<<<gG, 256, 0, stream>>>(g, Wo2, bo2, out, M);
}

// Round 2
// 328.446 us; speedup vs baseline: 1.2676x; 1.2676x over previous
//
#include <hip/hip_runtime.h>

// GCN 3-layer + MLP head.
// Round-2 changes vs round 1:
//  - g (the gathered buffer) is bf16: halves gather + g-write bytes.
//    dis[src] is no longer folded into g; k_agg gathers dis[src] per edge
//    (4B/edge, negligible) so the layer-1 GEMM no longer depends on the
//    CSR build -> k_count fuses under it.
//  - k_count fused into layer-1 GEMM dispatch (atomic-latency-bound count
//    overlaps VALU-bound GEMM).
//  - dis computed inside scan1 (drops a launch); csr scatter uses
//    nontemporal store to dodge write-allocate traffic.
// Math: out_i = dis_i*( sum_{e:dst=i} dis_src*graw_src + dis_i*graw_i ) + b
// where graw = h@W in bf16, accumulation fp32.

#define DHID 128

static __device__ __forceinline__ unsigned short f2bf(float f) {
  unsigned int u = __float_as_uint(f);
  u += 0x7fffu + ((u >> 16) & 1u);  // round-to-nearest-even
  return (unsigned short)(u >> 16);
}
static __device__ __forceinline__ float bf_lo(unsigned int v) {
  return __uint_as_float(v << 16);
}
static __device__ __forceinline__ float bf_hi(unsigned int v) {
  return __uint_as_float(v & 0xffff0000u);
}

// ---------------- CSR build ----------------

__global__ __launch_bounds__(256) void k_scan1(const int* __restrict__ cnt,
                                               int* __restrict__ rp,
                                               int* __restrict__ blk,
                                               float* __restrict__ dis, int M) {
  __shared__ int s[256];
  int tid = threadIdx.x;
  int i = blockIdx.x * 256 + tid;
  int v = (i < M) ? cnt[i] : 0;
  if (i < M) dis[i] = rsqrtf((float)v + 1.0f);
  s[tid] = v;
  __syncthreads();
  for (int off = 1; off < 256; off <<= 1) {
    int t = (tid >= off) ? s[tid - off] : 0;
    __syncthreads();
    s[tid] += t;
    __syncthreads();
  }
  if (i < M) rp[i] = s[tid] - v;  // exclusive within block
  if (tid == 255) blk[blockIdx.x] = s[255];
}

__global__ void k_scan2(int* blk, int n) {  // n <= 256
  __shared__ int s[256];
  int tid = threadIdx.x;
  int v = (tid < n) ? blk[tid] : 0;
  s[tid] = v;
  __syncthreads();
  for (int off = 1; off < 256; off <<= 1) {
    int t = (tid >= off) ? s[tid - off] : 0;
    __syncthreads();
    s[tid] += t;
    __syncthreads();
  }
  if (tid < n) blk[tid] = s[tid] - v;  // exclusive
}

__global__ __launch_bounds__(256) void k_scan3(int* __restrict__ rp,
                                               const int* __restrict__ blk,
                                               int* __restrict__ fill, int M, int E) {
  int i = blockIdx.x * 256 + threadIdx.x;
  if (i < M) {
    int v = rp[i] + blk[blockIdx.x];
    rp[i] = v;
    fill[i] = v;
  }
  if (i == 0) rp[M] = E;
}

__global__ __launch_bounds__(256) void k_fill(const int* __restrict__ ei, int E,
                                              int* __restrict__ fill,
                                              int* __restrict__ csr) {
  int e = blockIdx.x * 256 + threadIdx.x;
  if (e < E) {
    int d = ei[E + e];
    int pos = atomicAdd(&fill[d], 1);
    __builtin_nontemporal_store(ei[e], &csr[pos]);
  }
}

// ---------------- GEMM: [M,128] @ [128,128], fp32 vector FMA ----------------
// MODE 0: out = bf16(H@W)        (pre-aggregation graw buffer, ushort*)
// MODE 1: out = H@W + bias       (fp32, MLP hidden)
// 64 rows/block, 256 threads; thread = 8 rows x 4 cols; H tile in LDS.

template <int MODE>
__device__ __forceinline__ void gemm128_body(const float* __restrict__ H,
                                             const float* __restrict__ W,
                                             const float* __restrict__ bias,
                                             void* __restrict__ out, int M,
                                             int row0) {
  __shared__ float4 Hs[64 * 32];  // 32 KB
  int tid = threadIdx.x;
  const float4* H4 = (const float4*)H;
#pragma unroll
  for (int i = 0; i < 8; i++) {
    int slot = tid + i * 256;  // 0..2047
    int r = slot >> 5, c4 = slot & 31;
    int gr = row0 + r;
    Hs[slot] = (gr < M) ? H4[(size_t)gr * 32 + c4] : make_float4(0.f, 0.f, 0.f, 0.f);
  }
  __syncthreads();

  int c4 = tid & 31;          // output col group (4 cols)
  int r0 = (tid >> 5) * 8;    // 8 rows per thread
  const float4* W4 = (const float4*)W;  // W[k][c] row-major -> W4[k*32+c4]
  float4 acc[8];
#pragma unroll
  for (int r = 0; r < 8; r++) acc[r] = make_float4(0.f, 0.f, 0.f, 0.f);

  for (int k4 = 0; k4 < 32; k4++) {
    float4 w0 = W4[(k4 * 4 + 0) * 32 + c4];
    float4 w1 = W4[(k4 * 4 + 1) * 32 + c4];
    float4 w2 = W4[(k4 * 4 + 2) * 32 + c4];
    float4 w3 = W4[(k4 * 4 + 3) * 32 + c4];
#pragma unroll
    for (int r = 0; r < 8; r++) {
      float4 h = Hs[(r0 + r) * 32 + k4];
      acc[r].x = fmaf(h.w, w3.x, fmaf(h.z, w2.x, fmaf(h.y, w1.x, fmaf(h.x, w0.x, acc[r].x))));
      acc[r].y = fmaf(h.w, w3.y, fmaf(h.z, w2.y, fmaf(h.y, w1.y, fmaf(h.x, w0.y, acc[r].y))));
      acc[r].z = fmaf(h.w, w3.z, fmaf(h.z, w2.z, fmaf(h.y, w1.z, fmaf(h.x, w0.z, acc[r].z))));
      acc[r].w = fmaf(h.w, w3.w, fmaf(h.z, w2.w, fmaf(h.y, w1.w, fmaf(h.x, w0.w, acc[r].w))));
    }
  }

#pragma unroll
  for (int r = 0; r < 8; r++) {
    int gr = row0 + r0 + r;
    if (gr < M) {
      float4 v = acc[r];
      if (MODE == 0) {
        ushort4 o;
        o.x = f2bf(v.x); o.y = f2bf(v.y); o.z = f2bf(v.z); o.w = f2bf(v.w);
        ((ushort4*)out)[(size_t)gr * 32 + c4] = o;
      } else {
        float4 b = ((const float4*)bias)[c4];
        v.x += b.x; v.y += b.y; v.z += b.z; v.w += b.w;
        ((float4*)out)[(size_t)gr * 32 + c4] = v;
      }
    }
  }
}

template <int MODE>
__global__ __launch_bounds__(256) void k_gemm128(const float* __restrict__ H,
                                                 const float* __restrict__ W,
                                                 const float* __restrict__ bias,
                                                 void* __restrict__ out, int M) {
  gemm128_body<MODE>(H, W, bias, out, M, (int)blockIdx.x * 64);
}

// layer-1 GEMM fused with degree count: blocks [0,nG) do the GEMM tile,
// blocks [nG, nG+gE) do edge-count atomics (latency-bound, overlaps VALU).
__global__ __launch_bounds__(256) void k_gemm1_count(const float* __restrict__ H,
                                                     const float* __restrict__ W,
                                                     void* __restrict__ out, int M,
                                                     int nG, const int* __restrict__ ei,
                                                     int E, int* __restrict__ cnt) {
  if ((int)blockIdx.x >= nG) {
    int e = ((int)blockIdx.x - nG) * 256 + (int)threadIdx.x;
    if (e < E) atomicAdd(&cnt[ei[E + e]], 1);
    return;
  }
  gemm128_body<0>(H, W, nullptr, out, M, (int)blockIdx.x * 64);
}

// ---------------- GEMM: [M,128] @ [128,64] + bias -> out (fp32) ----------------
__global__ __launch_bounds__(256) void k_gemm64(const float* __restrict__ H,
                                                const float* __restrict__ W,
                                                const float* __restrict__ bias,
                                                float* __restrict__ out, int M) {
  __shared__ float4 Hs[64 * 32];  // 32 KB
  int tid = threadIdx.x;
  int row0 = blockIdx.x * 64;
  const float4* H4 = (const float4*)H;
#pragma unroll
  for (int i = 0; i < 8; i++) {
    int slot = tid + i * 256;
    int r = slot >> 5, c4 = slot & 31;
    int gr = row0 + r;
    Hs[slot] = (gr < M) ? H4[(size_t)gr * 32 + c4] : make_float4(0.f, 0.f, 0.f, 0.f);
  }
  __syncthreads();

  int c4 = tid & 15;         // 16 col groups x 4 = 64 cols
  int r0 = (tid >> 4) * 4;   // 16 row groups x 4 = 64 rows
  const float4* W4 = (const float4*)W;  // W[k][c], N=64 -> W4[k*16+c4]
  float4 acc[4];
#pragma unroll
  for (int r = 0; r < 4; r++) acc[r] = make_float4(0.f, 0.f, 0.f, 0.f);

  for (int k4 = 0; k4 < 32; k4++) {
    float4 w0 = W4[(k4 * 4 + 0) * 16 + c4];
    float4 w1 = W4[(k4 * 4 + 1) * 16 + c4];
    float4 w2 = W4[(k4 * 4 + 2) * 16 + c4];
    float4 w3 = W4[(k4 * 4 + 3) * 16 + c4];
#pragma unroll
    for (int r = 0; r < 4; r++) {
      float4 h = Hs[(r0 + r) * 32 + k4];
      acc[r].x = fmaf(h.w, w3.x, fmaf(h.z, w2.x, fmaf(h.y, w1.x, fmaf(h.x, w0.x, acc[r].x))));
      acc[r].y = fmaf(h.w, w3.y, fmaf(h.z, w2.y, fmaf(h.y, w1.y, fmaf(h.x, w0.y, acc[r].y))));
      acc[r].z = fmaf(h.w, w3.z, fmaf(h.z, w2.z, fmaf(h.y, w1.z, fmaf(h.x, w0.z, acc[r].z))));
      acc[r].w = fmaf(h.w, w3.w, fmaf(h.z, w2.w, fmaf(h.y, w1.w, fmaf(h.x, w0.w, acc[r].w))));
    }
  }

  float4 b = ((const float4*)bias)[c4];
#pragma unroll
  for (int r = 0; r < 4; r++) {
    int gr = row0 + r0 + r;
    if (gr < M) {
      float4 v = acc[r];
      v.x += b.x; v.y += b.y; v.z += b.z; v.w += b.w;
      ((float4*)out)[(size_t)gr * 16 + c4] = v;
    }
  }
}

// ---------------- Aggregation: one wave per node, bf16 gather ----------------
// h_out[i] = relu( dis_i*( sum_{e:dst=i} dis_src*graw_src + dis_i*graw_i ) + b )
__global__ __launch_bounds__(256) void k_agg(const unsigned short* __restrict__ g,
                                             const int* __restrict__ csr,
                                             const int* __restrict__ rp,
                                             const float* __restrict__ dis,
                                             const float* __restrict__ bias,
                                             float* __restrict__ out, int M, int relu) {
  int wid = (int)((blockIdx.x * 256 + threadIdx.x) >> 6);  // node id
  int lane = threadIdx.x & 63;
  if (wid >= M) return;
  const unsigned int* g1 = (const unsigned int*)g;  // 2 bf16 per uint; row = 64 uints
  float di = dis[wid];
  unsigned int self = g1[(size_t)wid * 64 + lane];
  float2 acc;
  acc.x = di * bf_lo(self);  // self-loop term dis_i * graw_i
  acc.y = di * bf_hi(self);
  int start = rp[wid], end = rp[wid + 1];
  for (int base = start; base < end; base += 64) {
    int n = end - base;
    if (n > 64) n = 64;
    int idx = 0;
    float dsv = 0.f;
    if (lane < n) {
      idx = csr[base + lane];
      dsv = dis[idx];
    }
    int j = 0;
    for (; j + 4 <= n; j += 4) {
      int s0 = __shfl(idx, j, 64);
      int s1 = __shfl(idx, j + 1, 64);
      int s2 = __shfl(idx, j + 2, 64);
      int s3 = __shfl(idx, j + 3, 64);
      float d0 = __shfl(dsv, j, 64);
      float d1 = __shfl(dsv, j + 1, 64);
      float d2 = __shfl(dsv, j + 2, 64);
      float d3 = __shfl(dsv, j + 3, 64);
      unsigned int v0 = g1[(size_t)s0 * 64 + lane];
      unsigned int v1 = g1[(size_t)s1 * 64 + lane];
      unsigned int v2 = g1[(size_t)s2 * 64 + lane];
      unsigned int v3 = g1[(size_t)s3 * 64 + lane];
      acc.x = fmaf(d0, bf_lo(v0), acc.x);
      acc.y = fmaf(d0, bf_hi(v0), acc.y);
      acc.x = fmaf(d1, bf_lo(v1), acc.x);
      acc.y = fmaf(d1, bf_hi(v1), acc.y);
      acc.x = fmaf(d2, bf_lo(v2), acc.x);
      acc.y = fmaf(d2, bf_hi(v2), acc.y);
      acc.x = fmaf(d3, bf_lo(v3), acc.x);
      acc.y = fmaf(d3, bf_hi(v3), acc.y);
    }
    for (; j < n; ++j) {
      int s0 = __shfl(idx, j, 64);
      float d0 = __shfl(dsv, j, 64);
      unsigned int v = g1[(size_t)s0 * 64 + lane];
      acc.x = fmaf(d0, bf_lo(v), acc.x);
      acc.y = fmaf(d0, bf_hi(v), acc.y);
    }
  }
  float2 b = ((const float2*)bias)[lane];
  float rx = fmaf(di, acc.x, b.x);
  float ry = fmaf(di, acc.y, b.y);
  if (relu) {
    rx = fmaxf(rx, 0.f);
    ry = fmaxf(ry, 0.f);
  }
  ((float2*)out)[(size_t)wid * 64 + lane] = make_float2(rx, ry);
}

// ---------------- launch ----------------

extern "C" void kernel_launch(void* const* d_in, const int* in_sizes, int n_in,
                              void* d_out, int out_size, void* d_ws, size_t ws_size,
                              hipStream_t stream) {
  const float* x = (const float*)d_in[0];
  const int* ei = (const int*)d_in[1];
  const float* W1 = (const float*)d_in[2];
  const float* b1 = (const float*)d_in[3];
  const float* W2 = (const float*)d_in[4];
  const float* b2 = (const float*)d_in[5];
  const float* W3 = (const float*)d_in[6];
  const float* b3 = (const float*)d_in[7];
  const float* Wo1 = (const float*)d_in[8];
  const float* bo1 = (const float*)d_in[9];
  const float* Wo2 = (const float*)d_in[10];
  const float* bo2 = (const float*)d_in[11];
  float* out = (float*)d_out;

  int M = in_sizes[0] / DHID;  // 50000
  int E = in_sizes[1] / 2;     // 800000

  // workspace layout (max 60.6 MB, same footprint as round 1)
  char* ws = (char*)d_ws;
  float* dis = (float*)(ws + 0);                       // M floats
  int* cnt = (int*)(ws + (1ull << 20));                // M ints
  int* rp = (int*)(ws + (2ull << 20));                 // M+1 ints
  int* fill = (int*)(ws + (3ull << 20));               // M ints
  int* blk = (int*)(ws + (4ull << 20));                // <=256 ints
  int* csr = (int*)(ws + (5ull << 20));                // E ints (3.2 MB)
  unsigned short* g = (unsigned short*)(ws + (9ull << 20));  // M*128 bf16 (12.8 MB)
  float* t = (float*)(ws + (9ull << 20));              // M*128 fp32 (25.6 MB), overlays dead g+csr in MLP phase
  float* h = (float*)(ws + (35ull << 20));             // M*128 fp32 (25.6 MB)

  int gE = (E + 255) / 256;
  int gM = (M + 255) / 256;   // 196 (<=256 required by k_scan2)
  int gG = (M + 63) / 64;     // GEMM row tiles
  int gA = (M + 3) / 4;       // 4 waves/block, wave per node

  // CSR build interleaved with layer-1 GEMM (gemm1 is CSR-independent)
  hipMemsetAsync(cnt, 0, (size_t)M * sizeof(int), stream);
  k_gemm1_count<<<gG + gE, 256, 0, stream>>>(x, W1, g, M, gG, ei, E, cnt);
  k_scan1<<<gM, 256, 0, stream>>>(cnt, rp, blk, dis, M);
  k_scan2<<<1, 256, 0, stream>>>(blk, gM);
  k_scan3<<<gM, 256, 0, stream>>>(rp, blk, fill, M, E);
  k_fill<<<gE, 256, 0, stream>>>(ei, E, fill, csr);

  // layer 1 aggregation
  k_agg<<<gA, 256, 0, stream>>>(g, csr, rp, dis, b1, h, M, 1);
  // GCN layer 2
  k_gemm128<0><<<gG, 256, 0, stream>>>(h, W2, nullptr, g, M);
  k_agg<<<gA, 256, 0, stream>>>(g, csr, rp, dis, b2, h, M, 1);
  // GCN layer 3
  k_gemm128<0><<<gG, 256, 0, stream>>>(h, W3, nullptr, g, M);
  k_agg<<<gA, 256, 0, stream>>>(g, csr, rp, dis, b3, h, M, 1);
  // MLP head (g and csr are dead; t overlays them)
  k_gemm128<1><<<gG, 256, 0, stream>>>(h, Wo1, bo1, t, M);
  k_gemm64<<<gG, 256, 0, stream>>>(t, Wo2, bo2, out, M);
}

// Round 3
// 273.503 us; speedup vs baseline: 1.5222x; 1.2009x over previous
//
#include <hip/hip_runtime.h>

// GCN 3-layer + MLP head.
// Round-3 change: CSR build via 2-level counting sort with block-sequential
// writes (fixes cross-XCD line thrash of the atomic scatter: round-2 k_fill
// wrote 61MB to HBM for a 3.2MB array, 66us).
//   pass1: per-block 256-bucket dst histogram (fused under layer-1 GEMM)
//   scan : exclusive scan of Hist[bucket][block] (50176 = 196x256)
//   pass2: re-read edges, LDS-claim slots, write (src,dst) bucket-grouped;
//          each (block,bucket) run is contiguous -> single-XCD lines
//   pass3: one block per bucket: LDS per-node count -> rp/dis, in-bucket
//          scatter -> csr (contiguous 12.5KB dest per block)
// Math: out_i = dis_i*( sum_{e:dst=i} dis_src*graw_src + dis_i*graw_i ) + b
// graw = h@W stored bf16; all accumulation fp32.

#define DHID 128
#define NBUK 256   // dst buckets
#define NBLK 196   // edge-chunk blocks (NBUK*NBLK = 50176 = 196*256 scan size)

static __device__ __forceinline__ unsigned short f2bf(float f) {
  unsigned int u = __float_as_uint(f);
  u += 0x7fffu + ((u >> 16) & 1u);  // round-to-nearest-even
  return (unsigned short)(u >> 16);
}
static __device__ __forceinline__ float bf_lo(unsigned int v) {
  return __uint_as_float(v << 16);
}
static __device__ __forceinline__ float bf_hi(unsigned int v) {
  return __uint_as_float(v & 0xffff0000u);
}

// ---------------- scan (generic, grid<=256 blocks of 256) ----------------

__global__ __launch_bounds__(256) void k_scan1(const int* __restrict__ in,
                                               int* __restrict__ out,
                                               int* __restrict__ blk, int Mtot) {
  __shared__ int s[256];
  int tid = threadIdx.x;
  int i = blockIdx.x * 256 + tid;
  int v = (i < Mtot) ? in[i] : 0;
  s[tid] = v;
  __syncthreads();
  for (int off = 1; off < 256; off <<= 1) {
    int t = (tid >= off) ? s[tid - off] : 0;
    __syncthreads();
    s[tid] += t;
    __syncthreads();
  }
  if (i < Mtot) out[i] = s[tid] - v;  // exclusive within block
  if (tid == 255) blk[blockIdx.x] = s[255];
}

__global__ void k_scan2(int* blk, int n) {  // n <= 256
  __shared__ int s[256];
  int tid = threadIdx.x;
  int v = (tid < n) ? blk[tid] : 0;
  s[tid] = v;
  __syncthreads();
  for (int off = 1; off < 256; off <<= 1) {
    int t = (tid >= off) ? s[tid - off] : 0;
    __syncthreads();
    s[tid] += t;
    __syncthreads();
  }
  if (tid < n) blk[tid] = s[tid] - v;  // exclusive
}

__global__ __launch_bounds__(256) void k_scan3(int* __restrict__ S,
                                               const int* __restrict__ blk, int Mtot) {
  int i = blockIdx.x * 256 + threadIdx.x;
  if (i < Mtot) S[i] += blk[blockIdx.x];
}

// ---------------- GEMM: [M,128] @ [128,128], fp32 vector FMA ----------------
// MODE 0: out = bf16(H@W)   MODE 1: out = H@W + bias (fp32)

template <int MODE>
__device__ __forceinline__ void gemm128_body(const float* __restrict__ H,
                                             const float* __restrict__ W,
                                             const float* __restrict__ bias,
                                             void* __restrict__ out, int M,
                                             int row0) {
  __shared__ float4 Hs[64 * 32];  // 32 KB
  int tid = threadIdx.x;
  const float4* H4 = (const float4*)H;
#pragma unroll
  for (int i = 0; i < 8; i++) {
    int slot = tid + i * 256;  // 0..2047
    int r = slot >> 5, c4 = slot & 31;
    int gr = row0 + r;
    Hs[slot] = (gr < M) ? H4[(size_t)gr * 32 + c4] : make_float4(0.f, 0.f, 0.f, 0.f);
  }
  __syncthreads();

  int c4 = tid & 31;          // output col group (4 cols)
  int r0 = (tid >> 5) * 8;    // 8 rows per thread
  const float4* W4 = (const float4*)W;  // W[k][c] row-major -> W4[k*32+c4]
  float4 acc[8];
#pragma unroll
  for (int r = 0; r < 8; r++) acc[r] = make_float4(0.f, 0.f, 0.f, 0.f);

  for (int k4 = 0; k4 < 32; k4++) {
    float4 w0 = W4[(k4 * 4 + 0) * 32 + c4];
    float4 w1 = W4[(k4 * 4 + 1) * 32 + c4];
    float4 w2 = W4[(k4 * 4 + 2) * 32 + c4];
    float4 w3 = W4[(k4 * 4 + 3) * 32 + c4];
#pragma unroll
    for (int r = 0; r < 8; r++) {
      float4 h = Hs[(r0 + r) * 32 + k4];
      acc[r].x = fmaf(h.w, w3.x, fmaf(h.z, w2.x, fmaf(h.y, w1.x, fmaf(h.x, w0.x, acc[r].x))));
      acc[r].y = fmaf(h.w, w3.y, fmaf(h.z, w2.y, fmaf(h.y, w1.y, fmaf(h.x, w0.y, acc[r].y))));
      acc[r].z = fmaf(h.w, w3.z, fmaf(h.z, w2.z, fmaf(h.y, w1.z, fmaf(h.x, w0.z, acc[r].z))));
      acc[r].w = fmaf(h.w, w3.w, fmaf(h.z, w2.w, fmaf(h.y, w1.w, fmaf(h.x, w0.w, acc[r].w))));
    }
  }

#pragma unroll
  for (int r = 0; r < 8; r++) {
    int gr = row0 + r0 + r;
    if (gr < M) {
      float4 v = acc[r];
      if (MODE == 0) {
        ushort4 o;
        o.x = f2bf(v.x); o.y = f2bf(v.y); o.z = f2bf(v.z); o.w = f2bf(v.w);
        ((ushort4*)out)[(size_t)gr * 32 + c4] = o;
      } else {
        float4 b = ((const float4*)bias)[c4];
        v.x += b.x; v.y += b.y; v.z += b.z; v.w += b.w;
        ((float4*)out)[(size_t)gr * 32 + c4] = v;
      }
    }
  }
}

template <int MODE>
__global__ __launch_bounds__(256) void k_gemm128(const float* __restrict__ H,
                                                 const float* __restrict__ W,
                                                 const float* __restrict__ bias,
                                                 void* __restrict__ out, int M) {
  gemm128_body<MODE>(H, W, bias, out, M, (int)blockIdx.x * 64);
}

// layer-1 GEMM fused with sort pass 1 (dst histogram). Blocks [0,nG): GEMM
// tile; blocks [nG, nG+NBLK): histogram chunk (latency/LDS-bound, overlaps
// the GEMM's VALU work).
__global__ __launch_bounds__(256) void k_gemm1_hist(const float* __restrict__ H,
                                                    const float* __restrict__ W,
                                                    void* __restrict__ out, int M,
                                                    int nG, const int* __restrict__ ei,
                                                    int E, int EPB, int NPB,
                                                    int* __restrict__ Hist) {
  if ((int)blockIdx.x >= nG) {
    __shared__ int hs[NBUK];
    int tid = threadIdx.x;
    int j = (int)blockIdx.x - nG;
    hs[tid] = 0;
    __syncthreads();
    int e0 = j * EPB;
    int e1 = min(e0 + EPB, E);
    for (int e = e0 + tid; e < e1; e += 256) {
      int d = ei[E + e];
      atomicAdd(&hs[d / NPB], 1);
    }
    __syncthreads();
    Hist[tid * NBLK + j] = hs[tid];
    return;
  }
  gemm128_body<0>(H, W, nullptr, out, M, (int)blockIdx.x * 64);
}

// sort pass 2: bucket-grouped scatter with block-sequential runs.
__global__ __launch_bounds__(256) void k_scatter(const int* __restrict__ ei, int E,
                                                 int EPB, int NPB,
                                                 const int* __restrict__ S,
                                                 int2* __restrict__ sorted) {
  __shared__ int run[NBUK];
  int tid = threadIdx.x;
  int j = blockIdx.x;
  run[tid] = S[tid * NBLK + j];
  __syncthreads();
  int e0 = j * EPB;
  int e1 = min(e0 + EPB, E);
  for (int e = e0 + tid; e < e1; e += 256) {
    int s = ei[e];
    int d = ei[E + e];
    int slot = atomicAdd(&run[d / NPB], 1);
    sorted[slot] = make_int2(s, d);
  }
}

// sort pass 3: per-bucket finalize -> rp, dis, csr.
__global__ __launch_bounds__(256) void k_finalize(const int2* __restrict__ sorted,
                                                  const int* __restrict__ S,
                                                  int E, int M, int NPB,
                                                  int* __restrict__ rp,
                                                  float* __restrict__ dis,
                                                  int* __restrict__ csr) {
  __shared__ int cnt[256];  // per-node counts (NPB <= 256)
  __shared__ int sc[256];
  int b = blockIdx.x;
  int tid = threadIdx.x;
  int node0 = b * NPB;
  int start = S[b * NBLK];
  int end = (b == NBUK - 1) ? E : S[(b + 1) * NBLK];
  cnt[tid] = 0;
  __syncthreads();
  for (int i = start + tid; i < end; i += 256) {
    atomicAdd(&cnt[sorted[i].y - node0], 1);
  }
  __syncthreads();
  int v = cnt[tid];
  sc[tid] = v;
  __syncthreads();
  for (int off = 1; off < 256; off <<= 1) {
    int t = (tid >= off) ? sc[tid - off] : 0;
    __syncthreads();
    sc[tid] += t;
    __syncthreads();
  }
  int lrp = sc[tid] - v;  // exclusive scan of per-node counts
  int node = node0 + tid;
  if (tid < NPB && node < M) {
    rp[node] = start + lrp;
    dis[node] = rsqrtf((float)v + 1.0f);
  }
  if (b == NBUK - 1 && tid == 0) rp[M] = E;
  __syncthreads();
  cnt[tid] = lrp;  // reuse as running slot counters
  __syncthreads();
  for (int i = start + tid; i < end; i += 256) {
    int2 p = sorted[i];
    int slot = atomicAdd(&cnt[p.y - node0], 1);
    csr[start + slot] = p.x;
  }
}

// ---------------- GEMM: [M,128] @ [128,64] + bias -> out (fp32) ----------------
__global__ __launch_bounds__(256) void k_gemm64(const float* __restrict__ H,
                                                const float* __restrict__ W,
                                                const float* __restrict__ bias,
                                                float* __restrict__ out, int M) {
  __shared__ float4 Hs[64 * 32];  // 32 KB
  int tid = threadIdx.x;
  int row0 = blockIdx.x * 64;
  const float4* H4 = (const float4*)H;
#pragma unroll
  for (int i = 0; i < 8; i++) {
    int slot = tid + i * 256;
    int r = slot >> 5, c4 = slot & 31;
    int gr = row0 + r;
    Hs[slot] = (gr < M) ? H4[(size_t)gr * 32 + c4] : make_float4(0.f, 0.f, 0.f, 0.f);
  }
  __syncthreads();

  int c4 = tid & 15;         // 16 col groups x 4 = 64 cols
  int r0 = (tid >> 4) * 4;   // 16 row groups x 4 = 64 rows
  const float4* W4 = (const float4*)W;  // W[k][c], N=64 -> W4[k*16+c4]
  float4 acc[4];
#pragma unroll
  for (int r = 0; r < 4; r++) acc[r] = make_float4(0.f, 0.f, 0.f, 0.f);

  for (int k4 = 0; k4 < 32; k4++) {
    float4 w0 = W4[(k4 * 4 + 0) * 16 + c4];
    float4 w1 = W4[(k4 * 4 + 1) * 16 + c4];
    float4 w2 = W4[(k4 * 4 + 2) * 16 + c4];
    float4 w3 = W4[(k4 * 4 + 3) * 16 + c4];
#pragma unroll
    for (int r = 0; r < 4; r++) {
      float4 h = Hs[(r0 + r) * 32 + k4];
      acc[r].x = fmaf(h.w, w3.x, fmaf(h.z, w2.x, fmaf(h.y, w1.x, fmaf(h.x, w0.x, acc[r].x))));
      acc[r].y = fmaf(h.w, w3.y, fmaf(h.z, w2.y, fmaf(h.y, w1.y, fmaf(h.x, w0.y, acc[r].y))));
      acc[r].z = fmaf(h.w, w3.z, fmaf(h.z, w2.z, fmaf(h.y, w1.z, fmaf(h.x, w0.z, acc[r].z))));
      acc[r].w = fmaf(h.w, w3.w, fmaf(h.z, w2.w, fmaf(h.y, w1.w, fmaf(h.x, w0.w, acc[r].w))));
    }
  }

  float4 b = ((const float4*)bias)[c4];
#pragma unroll
  for (int r = 0; r < 4; r++) {
    int gr = row0 + r0 + r;
    if (gr < M) {
      float4 v = acc[r];
      v.x += b.x; v.y += b.y; v.z += b.z; v.w += b.w;
      ((float4*)out)[(size_t)gr * 16 + c4] = v;
    }
  }
}

// ---------------- Aggregation: one wave per node, bf16 gather ----------------
__global__ __launch_bounds__(256) void k_agg(const unsigned short* __restrict__ g,
                                             const int* __restrict__ csr,
                                             const int* __restrict__ rp,
                                             const float* __restrict__ dis,
                                             const float* __restrict__ bias,
                                             float* __restrict__ out, int M, int relu) {
  int wid = (int)((blockIdx.x * 256 + threadIdx.x) >> 6);  // node id
  int lane = threadIdx.x & 63;
  if (wid >= M) return;
  const unsigned int* g1 = (const unsigned int*)g;  // 2 bf16 per uint; row = 64 uints
  float di = dis[wid];
  unsigned int self = g1[(size_t)wid * 64 + lane];
  float2 acc;
  acc.x = di * bf_lo(self);  // self-loop term dis_i * graw_i
  acc.y = di * bf_hi(self);
  int start = rp[wid], end = rp[wid + 1];
  for (int base = start; base < end; base += 64) {
    int n = end - base;
    if (n > 64) n = 64;
    int idx = 0;
    float dsv = 0.f;
    if (lane < n) {
      idx = csr[base + lane];
      dsv = dis[idx];
    }
    int j = 0;
    for (; j + 4 <= n; j += 4) {
      int s0 = __shfl(idx, j, 64);
      int s1 = __shfl(idx, j + 1, 64);
      int s2 = __shfl(idx, j + 2, 64);
      int s3 = __shfl(idx, j + 3, 64);
      float d0 = __shfl(dsv, j, 64);
      float d1 = __shfl(dsv, j + 1, 64);
      float d2 = __shfl(dsv, j + 2, 64);
      float d3 = __shfl(dsv, j + 3, 64);
      unsigned int v0 = g1[(size_t)s0 * 64 + lane];
      unsigned int v1 = g1[(size_t)s1 * 64 + lane];
      unsigned int v2 = g1[(size_t)s2 * 64 + lane];
      unsigned int v3 = g1[(size_t)s3 * 64 + lane];
      acc.x = fmaf(d0, bf_lo(v0), acc.x);
      acc.y = fmaf(d0, bf_hi(v0), acc.y);
      acc.x = fmaf(d1, bf_lo(v1), acc.x);
      acc.y = fmaf(d1, bf_hi(v1), acc.y);
      acc.x = fmaf(d2, bf_lo(v2), acc.x);
      acc.y = fmaf(d2, bf_hi(v2), acc.y);
      acc.x = fmaf(d3, bf_lo(v3), acc.x);
      acc.y = fmaf(d3, bf_hi(v3), acc.y);
    }
    for (; j < n; ++j) {
      int s0 = __shfl(idx, j, 64);
      float d0 = __shfl(dsv, j, 64);
      unsigned int v = g1[(size_t)s0 * 64 + lane];
      acc.x = fmaf(d0, bf_lo(v), acc.x);
      acc.y = fmaf(d0, bf_hi(v), acc.y);
    }
  }
  float2 b = ((const float2*)bias)[lane];
  float rx = fmaf(di, acc.x, b.x);
  float ry = fmaf(di, acc.y, b.y);
  if (relu) {
    rx = fmaxf(rx, 0.f);
    ry = fmaxf(ry, 0.f);
  }
  ((float2*)out)[(size_t)wid * 64 + lane] = make_float2(rx, ry);
}

// ---------------- launch ----------------

extern "C" void kernel_launch(void* const* d_in, const int* in_sizes, int n_in,
                              void* d_out, int out_size, void* d_ws, size_t ws_size,
                              hipStream_t stream) {
  const float* x = (const float*)d_in[0];
  const int* ei = (const int*)d_in[1];
  const float* W1 = (const float*)d_in[2];
  const float* b1 = (const float*)d_in[3];
  const float* W2 = (const float*)d_in[4];
  const float* b2 = (const float*)d_in[5];
  const float* W3 = (const float*)d_in[6];
  const float* b3 = (const float*)d_in[7];
  const float* Wo1 = (const float*)d_in[8];
  const float* bo1 = (const float*)d_in[9];
  const float* Wo2 = (const float*)d_in[10];
  const float* bo2 = (const float*)d_in[11];
  float* out = (float*)d_out;

  int M = in_sizes[0] / DHID;  // 50000
  int E = in_sizes[1] / 2;     // 800000

  int NPB = (M + NBUK - 1) / NBUK;       // nodes per bucket (196), <=256 for M<=65536
  int EPB = (E + NBLK - 1) / NBLK;       // edges per sort block
  int SCN = NBUK * NBLK;                 // 50176 scan elements (= 196 blocks x 256)

  // workspace layout (60.6 MB peak, same as round 2)
  char* ws = (char*)d_ws;
  float* dis = (float*)(ws + 0);                       // M floats
  int* rp = (int*)(ws + (1ull << 20));                 // M+1 ints
  int* Hist = (int*)(ws + (2ull << 20));               // SCN ints (200 KB)
  int* S = (int*)(ws + (3ull << 20));                  // SCN ints
  int* blk = (int*)(ws + (4ull << 20));                // <=256 ints
  int* csr = (int*)(ws + (5ull << 20));                // E ints (3.2 MB)
  unsigned short* g = (unsigned short*)(ws + (9ull << 20));  // M*128 bf16 (12.8 MB)
  int2* sorted = (int2*)(ws + (22ull << 20));          // E int2 (6.4 MB), dead after finalize
  float* t = (float*)(ws + (9ull << 20));              // M*128 fp32 (MLP phase only; overlays g+sorted)
  float* h = (float*)(ws + (35ull << 20));             // M*128 fp32 (25.6 MB)

  int gG = (M + 63) / 64;     // GEMM row tiles
  int gA = (M + 3) / 4;       // agg: 4 waves/block, wave per node

  // layer-1 GEMM fused with sort pass 1 (both CSR-chain and GEMM are
  // independent of each other)
  k_gemm1_hist<<<gG + NBLK, 256, 0, stream>>>(x, W1, g, M, gG, ei, E, EPB, NPB, Hist);
  // scan Hist -> S
  k_scan1<<<NBLK, 256, 0, stream>>>(Hist, S, blk, SCN);
  k_scan2<<<1, 256, 0, stream>>>(blk, NBLK);
  k_scan3<<<NBLK, 256, 0, stream>>>(S, blk, SCN);
  // sort pass 2 + 3
  k_scatter<<<NBLK, 256, 0, stream>>>(ei, E, EPB, NPB, S, sorted);
  k_finalize<<<NBUK, 256, 0, stream>>>(sorted, S, E, M, NPB, rp, dis, csr);

  // layer 1 aggregation
  k_agg<<<gA, 256, 0, stream>>>(g, csr, rp, dis, b1, h, M, 1);
  // GCN layer 2
  k_gemm128<0><<<gG, 256, 0, stream>>>(h, W2, nullptr, g, M);
  k_agg<<<gA, 256, 0, stream>>>(g, csr, rp, dis, b2, h, M, 1);
  // GCN layer 3
  k_gemm128<0><<<gG, 256, 0, stream>>>(h, W3, nullptr, g, M);
  k_agg<<<gA, 256, 0, stream>>>(g, csr, rp, dis, b3, h, M, 1);
  // MLP head (g, sorted, csr dead or unused by t's overlay region)
  k_gemm128<1><<<gG, 256, 0, stream>>>(h, Wo1, bo1, t, M);
  k_gemm64<<<gG, 256, 0, stream>>>(t, Wo2, bo2, out, M);
}